// Round 3
// baseline (434.480 us; speedup 1.0000x reference)
//
#include <hip/hip_runtime.h>

// Problem constants (match reference)
#define C_CLASSES 10000
#define K_PROTO   4
#define D_DIM     2048
#define ROWS      (C_CLASSES * K_PROTO)   // 40000
#define D_VEC     (D_DIM / 4)             // 512 float4 per row
#define NBLOCKS   (ROWS / 4)              // 4 waves/block, 1 row/wave -> 10000 blocks

typedef float v4f __attribute__((ext_vector_type(4)));

// Kernel 1: one wave per row, identical to the 408 us version EXCEPT the proto
// loads are plain cached loads instead of nontemporal. Single-variable probe:
// R0 (depth-32, nt) == R2 (depth-8, nt) == 408 us proved the kernel is
// insensitive to occupancy and pipeline depth; nt is the last shared variable.
__global__ __launch_bounds__(256) void dist_kernel(const v4f* __restrict__ proto,
                                                   const v4f* __restrict__ feat,
                                                   float* __restrict__ dout) {
    const int row  = (blockIdx.x << 2) | (threadIdx.x >> 6);   // 0..39999
    const int lane = threadIdx.x & 63;
    const v4f* p   = proto + (size_t)row * D_VEC;

    // HBM row loads first (in flight while feature loads resolve from L1/L2).
    v4f r[8];
#pragma unroll
    for (int j = 0; j < 8; ++j)
        r[j] = p[j * 64 + lane];

    v4f f[8];
#pragma unroll
    for (int j = 0; j < 8; ++j) f[j] = feat[j * 64 + lane];

    float a = 0.0f;
#pragma unroll
    for (int j = 0; j < 8; ++j) {
        const float dx = r[j].x - f[j].x;
        const float dy = r[j].y - f[j].y;
        const float dz = r[j].z - f[j].z;
        const float dw = r[j].w - f[j].w;
        a = fmaf(dx, dx, a);
        a = fmaf(dy, dy, a);
        a = fmaf(dz, dz, a);
        a = fmaf(dw, dw, a);
    }

#pragma unroll
    for (int m = 1; m <= 32; m <<= 1) a += __shfl_xor(a, m, 64);

    if (lane == 0) dout[row] = a;
}

// Kernel 2: one 1024-thread block does the full logsumexp over 40000 d's
// (160 KB, L2-hot) and the label-row sum. Two passes: global min, then
// sum of exp(dmin - d). probability = sum_k (log_one + d[label*4+k]).
__global__ __launch_bounds__(1024) void finalize_kernel(const float4* __restrict__ d4,
                                                        const int* __restrict__ label,
                                                        float* __restrict__ out) {
    __shared__ float sm[20];
    const int tid  = threadIdx.x;
    const int lane = tid & 63;
    const int wid  = tid >> 6;          // 0..15
    const int N4   = ROWS / 4;          // 10000 float4

    // Pass 1: global min of d.
    float m = 3.402823466e38f;
    for (int i = tid; i < N4; i += 1024) {
        const float4 p = d4[i];
        m = fminf(m, fminf(fminf(p.x, p.y), fminf(p.z, p.w)));
    }
#pragma unroll
    for (int off = 1; off < 64; off <<= 1) m = fminf(m, __shfl_xor(m, off, 64));
    if (lane == 0) sm[wid] = m;
    __syncthreads();
    if (tid == 0) {
        float mm = sm[0];
#pragma unroll
        for (int i = 1; i < 16; ++i) mm = fminf(mm, sm[i]);
        sm[16] = mm;
    }
    __syncthreads();
    const float dmin = sm[16];

    // Pass 2: sum of exp(dmin - d).
    float acc = 0.0f;
    for (int i = tid; i < N4; i += 1024) {
        const float4 p = d4[i];
        acc += expf(dmin - p.x) + expf(dmin - p.y) + expf(dmin - p.z) + expf(dmin - p.w);
    }
#pragma unroll
    for (int off = 1; off < 64; off <<= 1) acc += __shfl_xor(acc, off, 64);
    if (lane == 0) sm[wid] = acc;
    __syncthreads();
    if (tid == 0) {
        float ss = 0.0f;
#pragma unroll
        for (int i = 0; i < 16; ++i) ss += sm[i];
        const float log_one = -dmin + logf(ss);
        const float* d = (const float*)d4;
        const int lbl = label[0];
        float p = 0.0f;
#pragma unroll
        for (int k = 0; k < K_PROTO; ++k) p += log_one + d[lbl * K_PROTO + k];
        out[0] = p;
    }
}

extern "C" void kernel_launch(void* const* d_in, const int* in_sizes, int n_in,
                              void* d_out, int out_size, void* d_ws, size_t ws_size,
                              hipStream_t stream) {
    const float* feat  = (const float*)d_in[0];   // [2048] f32
    const int*   label = (const int*)d_in[1];     // [1] int32
    const float* proto = (const float*)d_in[2];   // [10000,4,2048] f32
    float* out = (float*)d_out;                   // [1] f32

    float* d = (float*)d_ws;                      // [40000] squared distances

    dist_kernel<<<NBLOCKS, 256, 0, stream>>>((const v4f*)proto, (const v4f*)feat, d);
    finalize_kernel<<<1, 1024, 0, stream>>>((const float4*)d, label, out);
}

// Round 4
// 405.029 us; speedup vs baseline: 1.0727x; 1.0727x over previous
//
#include <hip/hip_runtime.h>

// Problem constants (match reference)
#define C_CLASSES 10000
#define K_PROTO   4
#define D_DIM     2048
#define ROWS      (C_CLASSES * K_PROTO)   // 40000
#define D_VEC     (D_DIM / 4)             // 512 float4 per row
#define NBLOCKS   (ROWS / 4)              // 4 waves/block, 1 row/wave -> 10000 blocks

typedef float v4f __attribute__((ext_vector_type(4)));

// Kernel 1: one wave per row — identical to the 408 us best EXCEPT proto loads
// are emitted as inline-asm global_load_dwordx4 with `nt sc0 sc1` (full
// streaming / system-scope: no L2 allocation). Theory: the harness's 1.31 GB
// ws-poison fill leaves L2+LLC dirty; allocating reads force dirty-victim
// writebacks onto the read path (~1.7 TB/s effective). nt alone (still
// allocating, evict-first) bought 26 us; sc0+sc1+nt should skip the victim
// path entirely. LLC on MI355X is memory-side, so bypass costs nothing for
// zero-reuse data.
__global__ __launch_bounds__(256) void dist_kernel(const v4f* __restrict__ proto,
                                                   const v4f* __restrict__ feat,
                                                   float* __restrict__ dout) {
    const int row  = (blockIdx.x << 2) | (threadIdx.x >> 6);   // 0..39999
    const int lane = threadIdx.x & 63;

    // Per-lane base addresses: row start + lane*16B; second base +4 KB so all
    // eight 1 KB-strided loads fit the 13-bit signed offset immediate.
    const float* pa = (const float*)proto + (size_t)row * D_DIM + lane * 4;
    const float* pb = pa + 1024;   // +4096 bytes

    v4f r0, r1, r2, r3, r4, r5, r6, r7;
    asm volatile(
        "global_load_dwordx4 %[d0], %[a], off nt sc0 sc1\n\t"
        "global_load_dwordx4 %[d1], %[a], off offset:1024 nt sc0 sc1\n\t"
        "global_load_dwordx4 %[d2], %[a], off offset:2048 nt sc0 sc1\n\t"
        "global_load_dwordx4 %[d3], %[a], off offset:3072 nt sc0 sc1\n\t"
        "global_load_dwordx4 %[d4], %[b], off nt sc0 sc1\n\t"
        "global_load_dwordx4 %[d5], %[b], off offset:1024 nt sc0 sc1\n\t"
        "global_load_dwordx4 %[d6], %[b], off offset:2048 nt sc0 sc1\n\t"
        "global_load_dwordx4 %[d7], %[b], off offset:3072 nt sc0 sc1"
        : [d0] "=&v"(r0), [d1] "=&v"(r1), [d2] "=&v"(r2), [d3] "=&v"(r3),
          [d4] "=&v"(r4), [d5] "=&v"(r5), [d6] "=&v"(r6), [d7] "=&v"(r7)
        : [a] "v"(pa), [b] "v"(pb));

    // Feature loads (normal cached path — reused by every wave, L2-hot).
    v4f f[8];
#pragma unroll
    for (int j = 0; j < 8; ++j) f[j] = feat[j * 64 + lane];

    // Drain our asm loads before any consumer; fence the scheduler so FMAs
    // can't be hoisted above the waitcnt (guide rule #18).
    asm volatile("s_waitcnt vmcnt(0)" ::: "memory");
    __builtin_amdgcn_sched_barrier(0);

    const v4f r[8] = {r0, r1, r2, r3, r4, r5, r6, r7};
    float a = 0.0f;
#pragma unroll
    for (int j = 0; j < 8; ++j) {
        const float dx = r[j].x - f[j].x;
        const float dy = r[j].y - f[j].y;
        const float dz = r[j].z - f[j].z;
        const float dw = r[j].w - f[j].w;
        a = fmaf(dx, dx, a);
        a = fmaf(dy, dy, a);
        a = fmaf(dz, dz, a);
        a = fmaf(dw, dw, a);
    }

#pragma unroll
    for (int m = 1; m <= 32; m <<= 1) a += __shfl_xor(a, m, 64);

    if (lane == 0) dout[row] = a;
}

// Kernel 2: one 1024-thread block does the full logsumexp over 40000 d's
// (160 KB, L2-hot) and the label-row sum. Two passes: global min, then
// sum of exp(dmin - d). probability = sum_k (log_one + d[label*4+k]).
__global__ __launch_bounds__(1024) void finalize_kernel(const float4* __restrict__ d4,
                                                        const int* __restrict__ label,
                                                        float* __restrict__ out) {
    __shared__ float sm[20];
    const int tid  = threadIdx.x;
    const int lane = tid & 63;
    const int wid  = tid >> 6;          // 0..15
    const int N4   = ROWS / 4;          // 10000 float4

    // Pass 1: global min of d.
    float m = 3.402823466e38f;
    for (int i = tid; i < N4; i += 1024) {
        const float4 p = d4[i];
        m = fminf(m, fminf(fminf(p.x, p.y), fminf(p.z, p.w)));
    }
#pragma unroll
    for (int off = 1; off < 64; off <<= 1) m = fminf(m, __shfl_xor(m, off, 64));
    if (lane == 0) sm[wid] = m;
    __syncthreads();
    if (tid == 0) {
        float mm = sm[0];
#pragma unroll
        for (int i = 1; i < 16; ++i) mm = fminf(mm, sm[i]);
        sm[16] = mm;
    }
    __syncthreads();
    const float dmin = sm[16];

    // Pass 2: sum of exp(dmin - d).
    float acc = 0.0f;
    for (int i = tid; i < N4; i += 1024) {
        const float4 p = d4[i];
        acc += expf(dmin - p.x) + expf(dmin - p.y) + expf(dmin - p.z) + expf(dmin - p.w);
    }
#pragma unroll
    for (int off = 1; off < 64; off <<= 1) acc += __shfl_xor(acc, off, 64);
    if (lane == 0) sm[wid] = acc;
    __syncthreads();
    if (tid == 0) {
        float ss = 0.0f;
#pragma unroll
        for (int i = 0; i < 16; ++i) ss += sm[i];
        const float log_one = -dmin + logf(ss);
        const float* d = (const float*)d4;
        const int lbl = label[0];
        float p = 0.0f;
#pragma unroll
        for (int k = 0; k < K_PROTO; ++k) p += log_one + d[lbl * K_PROTO + k];
        out[0] = p;
    }
}

extern "C" void kernel_launch(void* const* d_in, const int* in_sizes, int n_in,
                              void* d_out, int out_size, void* d_ws, size_t ws_size,
                              hipStream_t stream) {
    const float* feat  = (const float*)d_in[0];   // [2048] f32
    const int*   label = (const int*)d_in[1];     // [1] int32
    const float* proto = (const float*)d_in[2];   // [10000,4,2048] f32
    float* out = (float*)d_out;                   // [1] f32

    float* d = (float*)d_ws;                      // [40000] squared distances

    dist_kernel<<<NBLOCKS, 256, 0, stream>>>((const v4f*)proto, (const v4f*)feat, d);
    finalize_kernel<<<1, 1024, 0, stream>>>((const float4*)d, label, out);
}